// Round 2
// baseline (1247.436 us; speedup 1.0000x reference)
//
#include <hip/hip_runtime.h>
#include <hip/hip_bf16.h>

#define H_DIM 2048
#define N_HEADS 16
#define HEAD_DIM 128
#define BATCH 2
#define SEQ 2048

typedef __bf16 bf16_t;
typedef __bf16 bf16x8 __attribute__((ext_vector_type(8)));
typedef float f32x4 __attribute__((ext_vector_type(4)));

#define MFMA16(a, b, c) __builtin_amdgcn_mfma_f32_16x16x32_bf16((a), (b), (c), 0, 0, 0)

// Detect whether float tensors are stored as bf16 (flag=1) or fp32 (flag=0).
// For bf16 storage, the low 16 bits of a 32-bit word is a bf16 of ~N(0,1):
// exponent field in [100,141] essentially always. For fp32 storage the low
// 16 bits are uniform mantissa bits: ~16% hit that range. 4096 words -> the
// two distributions are ~58 sigma apart at threshold 2048.
__global__ __launch_bounds__(256) void detect_kernel(const unsigned int* __restrict__ X,
                                                     int* __restrict__ flag) {
    __shared__ int cnt[256];
    int t = threadIdx.x;
    int c = 0;
    for (int i = 0; i < 16; i++) {
        unsigned w  = X[t * 16 + i];
        unsigned lo = w & 0xFFFFu;
        unsigned e  = (lo >> 7) & 0xFFu;
        if (lo == 0u || (e >= 100u && e <= 141u)) c++;
    }
    cnt[t] = c;
    __syncthreads();
    for (int s = 128; s > 0; s >>= 1) {
        if (t < s) cnt[t] += cnt[t + s];
        __syncthreads();
    }
    if (t == 0) *flag = (cnt[0] >= 2048) ? 1 : 0;
}

// Load 8 consecutive elements starting at element index idx, as bf16x8,
// from either a bf16 buffer or an fp32 buffer (converted RNE).
__device__ inline bf16x8 load8(const void* __restrict__ p, size_t idx, int isbf16) {
    if (isbf16) {
        return *(const bf16x8*)((const bf16_t*)p + idx);
    } else {
        const float* f = (const float*)p + idx;
        float4 a = *(const float4*)f;
        float4 b = *(const float4*)(f + 4);
        bf16x8 r;
        r[0] = (bf16_t)a.x; r[1] = (bf16_t)a.y; r[2] = (bf16_t)a.z; r[3] = (bf16_t)a.w;
        r[4] = (bf16_t)b.x; r[5] = (bf16_t)b.y; r[6] = (bf16_t)b.z; r[7] = (bf16_t)b.w;
        return r;
    }
}

// C[M,N] = A[M,K] * W[K,N] + bias[N]
// mode 0: store C row-major [M,N] (dtype per flag: bf16 or fp32)
// mode 1: scatter C -> [B][N_HEADS][SEQ][HEAD_DIM], always bf16 (workspace)
// a_forced_bf16: A is workspace bf16 regardless of flag (final projection).
__global__ __launch_bounds__(256) void gemm_bias_kernel(
    const void* __restrict__ A, const void* __restrict__ W,
    const void* __restrict__ bias, void* __restrict__ C,
    const int* __restrict__ flagPtr, int a_forced_bf16,
    int M, int N, int K, int mode)
{
    const int isbf16 = *flagPtr;
    const int a_bf   = a_forced_bf16 | isbf16;

    // quad-major LDS layout: [kquad][row][8 contiguous k] -> ds_read_b128
    __shared__ __attribute__((aligned(16))) bf16_t As2[4][64][8];
    __shared__ __attribute__((aligned(16))) bf16_t Wt2[4][64][8];

    const int tid  = threadIdx.x;
    const int lane = tid & 63;
    const int wid  = tid >> 6;
    const int quad = lane >> 4;
    const int l16  = lane & 15;
    const int wm   = (wid >> 1) * 32;
    const int wn   = (wid & 1) * 32;
    const int m0   = blockIdx.y * 64;
    const int n0   = blockIdx.x * 64;

    const int a_row  = tid >> 2;
    const int a_q    = tid & 3;
    const int w_krow = tid >> 3;
    const int w_nc   = (tid & 7) * 8;

    f32x4 acc[2][2] = {};

    for (int k0 = 0; k0 < K; k0 += 32) {
        bf16x8 av = load8(A, (size_t)(m0 + a_row) * K + k0 + a_q * 8, a_bf);
        bf16x8 wv = load8(W, (size_t)(k0 + w_krow) * N + n0 + w_nc, isbf16);
        __syncthreads();   // previous iteration's LDS reads complete
        *(bf16x8*)(&As2[a_q][a_row][0]) = av;
        #pragma unroll
        for (int jj = 0; jj < 8; jj++)
            Wt2[w_krow >> 3][w_nc + jj][w_krow & 7] = wv[jj];
        __syncthreads();

        bf16x8 a0 = *(const bf16x8*)(&As2[quad][wm + l16][0]);
        bf16x8 a1 = *(const bf16x8*)(&As2[quad][wm + 16 + l16][0]);
        bf16x8 b0 = *(const bf16x8*)(&Wt2[quad][wn + l16][0]);
        bf16x8 b1 = *(const bf16x8*)(&Wt2[quad][wn + 16 + l16][0]);
        acc[0][0] = MFMA16(a0, b0, acc[0][0]);
        acc[0][1] = MFMA16(a0, b1, acc[0][1]);
        acc[1][0] = MFMA16(a1, b0, acc[1][0]);
        acc[1][1] = MFMA16(a1, b1, acc[1][1]);
    }

    // C/D layout: col = lane&15, row = quad*4 + reg  (m89/m91 verified)
    #pragma unroll
    for (int mt = 0; mt < 2; mt++) {
        #pragma unroll
        for (int nt = 0; nt < 2; nt++) {
            int col = n0 + wn + nt * 16 + l16;
            float bv = isbf16 ? (float)((const bf16_t*)bias)[col]
                              : ((const float*)bias)[col];
            #pragma unroll
            for (int r = 0; r < 4; r++) {
                int row = m0 + wm + mt * 16 + quad * 4 + r;
                float v = acc[mt][nt][r] + bv;
                if (mode == 0) {
                    if (isbf16) ((bf16_t*)C)[(size_t)row * N + col] = (bf16_t)v;
                    else        ((float*)C)[(size_t)row * N + col]  = v;
                } else {
                    int b = row >> 11, s = row & (SEQ - 1);
                    int h = col >> 7,  d = col & (HEAD_DIM - 1);
                    ((bf16_t*)C)[((size_t)(b * N_HEADS + h) * SEQ + s) * HEAD_DIM + d] = (bf16_t)v;
                }
            }
        }
    }
}

// Flash-style attention. Q,K,V in [B,H,S,D] bf16 (workspace). ctx out [B,S,H,D] bf16.
__global__ __launch_bounds__(256) void attn_kernel(
    const bf16_t* __restrict__ Q, const bf16_t* __restrict__ Kt,
    const bf16_t* __restrict__ V, const int* __restrict__ mask,
    bf16_t* __restrict__ ctx)
{
    __shared__ __attribute__((aligned(16))) bf16_t Vt[HEAD_DIM][72]; // [d][key]
    __shared__ __attribute__((aligned(16))) bf16_t Pl[4][16][72];    // per-wave P

    const int tid  = threadIdx.x;
    const int lane = tid & 63;
    const int wid  = tid >> 6;
    const int quad = lane >> 4;
    const int l16  = lane & 15;

    const int bh = blockIdx.y;
    const int b  = bh >> 4, h = bh & 15;
    const int q_base = blockIdx.x * 64 + wid * 16;

    const bf16_t* Qp = Q  + (size_t)bh * SEQ * HEAD_DIM;
    const bf16_t* Kp = Kt + (size_t)bh * SEQ * HEAD_DIM;
    const bf16_t* Vp = V  + (size_t)bh * SEQ * HEAD_DIM;
    const int*    mp = mask + (size_t)b * SEQ * SEQ;

    // Q fragments: A-operand A[m=lane&15][k=quad*8+j], 4 k-steps over D=128
    bf16x8 qf[4];
    #pragma unroll
    for (int t = 0; t < 4; t++)
        qf[t] = *(const bf16x8*)(Qp + (size_t)(q_base + l16) * HEAD_DIM + t * 32 + quad * 8);

    float m_r[4], l_r[4];
    #pragma unroll
    for (int r = 0; r < 4; r++) { m_r[r] = -1e30f; l_r[r] = 0.0f; }
    f32x4 o_acc[8] = {};

    for (int kt = 0; kt < SEQ / 64; kt++) {
        const int key0 = kt * 64;
        __syncthreads();   // prev-iter Vt/Pl reads complete
        #pragma unroll
        for (int i = 0; i < 4; i++) {
            int vv  = tid + 256 * i;
            int key = vv >> 4;
            int dv  = (vv & 15) * 8;
            bf16x8 val = *(const bf16x8*)(Vp + (size_t)(key0 + key) * HEAD_DIM + dv);
            #pragma unroll
            for (int jj = 0; jj < 8; jj++)
                Vt[dv + jj][key] = val[jj];
        }

        // S = Q K^T: B-operand from K rows: B[n=lane&15][k=quad*8+j]
        f32x4 s_acc[4];
        #pragma unroll
        for (int nt = 0; nt < 4; nt++) {
            f32x4 a = {};
            #pragma unroll
            for (int t = 0; t < 4; t++) {
                bf16x8 kf = *(const bf16x8*)(Kp + (size_t)(key0 + nt * 16 + l16) * HEAD_DIM + t * 32 + quad * 8);
                a = MFMA16(qf[t], kf, a);
            }
            s_acc[nt] = a;
        }

        float p[4][4];
        #pragma unroll
        for (int nt = 0; nt < 4; nt++) {
            int key = key0 + nt * 16 + l16;
            #pragma unroll
            for (int r = 0; r < 4; r++) {
                int q = q_base + quad * 4 + r;
                float s = s_acc[nt][r] * 0.08838834764831845f;
                if (mp[(size_t)q * SEQ + key] == 0) s = -1e30f;
                p[nt][r] = s;
            }
        }

        #pragma unroll
        for (int r = 0; r < 4; r++) {
            float tmax = fmaxf(fmaxf(p[0][r], p[1][r]), fmaxf(p[2][r], p[3][r]));
            #pragma unroll
            for (int off = 1; off < 16; off <<= 1)
                tmax = fmaxf(tmax, __shfl_xor(tmax, off));
            float mnew  = fmaxf(m_r[r], tmax);
            float alpha = __expf(m_r[r] - mnew);
            m_r[r] = mnew;
            float rsum = 0.0f;
            #pragma unroll
            for (int nt = 0; nt < 4; nt++) {
                float pv = __expf(p[nt][r] - mnew);
                p[nt][r] = pv;
                rsum += pv;
            }
            #pragma unroll
            for (int off = 1; off < 16; off <<= 1)
                rsum += __shfl_xor(rsum, off);
            l_r[r] = l_r[r] * alpha + rsum;
            #pragma unroll
            for (int dn = 0; dn < 8; dn++)
                o_acc[dn][r] *= alpha;
        }

        // P: C-layout -> LDS -> A-layout (m120-verified transform)
        #pragma unroll
        for (int nt = 0; nt < 4; nt++)
            #pragma unroll
            for (int r = 0; r < 4; r++)
                Pl[wid][quad * 4 + r][nt * 16 + l16] = (bf16_t)p[nt][r];
        __syncthreads();

        // O += P V
        #pragma unroll
        for (int t = 0; t < 2; t++) {
            bf16x8 pf = *(const bf16x8*)(&Pl[wid][l16][t * 32 + quad * 8]);
            #pragma unroll
            for (int dn = 0; dn < 8; dn++) {
                bf16x8 vf = *(const bf16x8*)(&Vt[dn * 16 + l16][t * 32 + quad * 8]);
                o_acc[dn] = MFMA16(pf, vf, o_acc[dn]);
            }
        }
    }

    #pragma unroll
    for (int dn = 0; dn < 8; dn++) {
        #pragma unroll
        for (int r = 0; r < 4; r++) {
            int q = q_base + quad * 4 + r;
            int d = dn * 16 + l16;
            float v = o_acc[dn][r] / l_r[r];
            ctx[((size_t)(b * SEQ + q) * N_HEADS + h) * HEAD_DIM + d] = (bf16_t)v;
        }
    }
}

extern "C" void kernel_launch(void* const* d_in, const int* in_sizes, int n_in,
                              void* d_out, int out_size, void* d_ws, size_t ws_size,
                              hipStream_t stream) {
    const void* X    = d_in[0];
    const int*  mask = (const int*)d_in[1];
    const void* Wq   = d_in[2];
    const void* bq   = d_in[3];
    const void* Wk   = d_in[4];
    const void* bk   = d_in[5];
    const void* Wv   = d_in[6];
    const void* bv   = d_in[7];
    const void* Wo   = d_in[8];
    const void* bo   = d_in[9];

    int* flag = (int*)d_ws;
    const size_t NE = (size_t)BATCH * SEQ * H_DIM;   // 8388608 elems
    bf16_t* qws = (bf16_t*)((char*)d_ws + 256);      // [B,H,S,D]
    bf16_t* kws = qws + NE;
    bf16_t* vws = kws + NE;
    bf16_t* cws = vws + NE;                          // ctx [B,S,H,D]

    const int M = BATCH * SEQ;
    dim3 gg(H_DIM / 64, M / 64);

    detect_kernel<<<1, 256, 0, stream>>>((const unsigned int*)X, flag);
    gemm_bias_kernel<<<gg, 256, 0, stream>>>(X, Wq, bq, qws, flag, 0, M, H_DIM, H_DIM, 1);
    gemm_bias_kernel<<<gg, 256, 0, stream>>>(X, Wk, bk, kws, flag, 0, M, H_DIM, H_DIM, 1);
    gemm_bias_kernel<<<gg, 256, 0, stream>>>(X, Wv, bv, vws, flag, 0, M, H_DIM, H_DIM, 1);
    attn_kernel<<<dim3(SEQ / 64, BATCH * N_HEADS), 256, 0, stream>>>(qws, kws, vws, mask, cws);
    gemm_bias_kernel<<<gg, 256, 0, stream>>>(cws, Wo, bo, d_out, flag, 1, M, H_DIM, H_DIM, 0);
}

// Round 3
// 1174.532 us; speedup vs baseline: 1.0621x; 1.0621x over previous
//
#include <hip/hip_runtime.h>
#include <hip/hip_bf16.h>

#define H_DIM 2048
#define N_HEADS 16
#define HEAD_DIM 128
#define BATCH 2
#define SEQ 2048

typedef __bf16 bf16_t;
typedef __bf16 bf16x8 __attribute__((ext_vector_type(8)));
typedef float f32x4 __attribute__((ext_vector_type(4)));

#define MFMA16(a, b, c) __builtin_amdgcn_mfma_f32_16x16x32_bf16((a), (b), (c), 0, 0, 0)

// async global->LDS, 16 B per lane. LDS side must be uniform-base + lane*16.
#define GLOAD16(gp, lp) __builtin_amdgcn_global_load_lds( \
    (const __attribute__((address_space(1))) void*)(gp),  \
    (__attribute__((address_space(3))) void*)(lp), 16, 0, 0)

// flags[0] = inputs stored as bf16 (1) or fp32 (0); flags[1] = mask all-ones
__global__ __launch_bounds__(256) void detect_kernel(const unsigned int* __restrict__ X,
                                                     int* __restrict__ flags) {
    __shared__ int cnt[256];
    int t = threadIdx.x;
    int c = 0;
    for (int i = 0; i < 16; i++) {
        unsigned w  = X[t * 16 + i];
        unsigned lo = w & 0xFFFFu;
        unsigned e  = (lo >> 7) & 0xFFu;
        if (lo == 0u || (e >= 100u && e <= 141u)) c++;
    }
    cnt[t] = c;
    __syncthreads();
    for (int s = 128; s > 0; s >>= 1) {
        if (t < s) cnt[t] += cnt[t + s];
        __syncthreads();
    }
    if (t == 0) { flags[0] = (cnt[0] >= 2048) ? 1 : 0; flags[1] = 1; }
}

__global__ __launch_bounds__(256) void maskcheck_kernel(const int* __restrict__ mask,
                                                        int* __restrict__ flags) {
    size_t i = ((size_t)blockIdx.x * 256 + threadIdx.x) * 8;
    const int4* p = (const int4*)(mask + i);
    int4 a = p[0], b = p[1];
    int all = (a.x != 0) & (a.y != 0) & (a.z != 0) & (a.w != 0) &
              (b.x != 0) & (b.y != 0) & (b.z != 0) & (b.w != 0);
    if (!all) atomicAnd(&flags[1], 0);
}

__device__ inline bf16x8 load8(const void* __restrict__ p, size_t idx, int isbf16) {
    if (isbf16) {
        return *(const bf16x8*)((const bf16_t*)p + idx);
    } else {
        const float* f = (const float*)p + idx;
        float4 a = *(const float4*)f;
        float4 b = *(const float4*)(f + 4);
        bf16x8 r;
        r[0] = (bf16_t)a.x; r[1] = (bf16_t)a.y; r[2] = (bf16_t)a.z; r[3] = (bf16_t)a.w;
        r[4] = (bf16_t)b.x; r[5] = (bf16_t)b.y; r[6] = (bf16_t)b.z; r[7] = (bf16_t)b.w;
        return r;
    }
}

__device__ inline float readf(const void* __restrict__ p, int idx, int isbf16) {
    return isbf16 ? (float)((const bf16_t*)p)[idx] : ((const float*)p)[idx];
}

// X (fp32 or bf16) -> Xb (bf16), 8 elems/thread
__global__ __launch_bounds__(256) void convert_kernel(const void* __restrict__ X,
                                                      bf16_t* __restrict__ Xb,
                                                      const int* __restrict__ flags) {
    const int isbf16 = flags[0];
    size_t i = ((size_t)blockIdx.x * 256 + threadIdx.x) * 8;
    bf16x8 v = load8(X, i, isbf16);
    *(bf16x8*)(Xb + i) = v;
}

// Wt[z][n][k] = W_z[k][n], bf16 output. grid (32,32,4), 64x64 tiles.
__global__ __launch_bounds__(256) void transpose_kernel(
    const void* __restrict__ W0, const void* __restrict__ W1,
    const void* __restrict__ W2, const void* __restrict__ W3,
    bf16_t* __restrict__ Wts, const int* __restrict__ flags)
{
    const int isbf16 = flags[0];
    const int z = blockIdx.z;
    const void* W = (z == 0) ? W0 : (z == 1) ? W1 : (z == 2) ? W2 : W3;
    bf16_t* out = Wts + (size_t)z * H_DIM * H_DIM;

    __shared__ __attribute__((aligned(16))) bf16_t Ts[64][72];  // pad: 144B stride
    const int tid = threadIdx.x;
    const int n0 = blockIdx.x * 64;
    const int k0 = blockIdx.y * 64;

    // load: rows of W (k-major), coalesced; Ts[r=k][c=n]
    #pragma unroll
    for (int j = 0; j < 2; j++) {
        int idx = j * 2048 + tid * 8;
        int r = idx >> 6, c = idx & 63;
        bf16x8 v = load8(W, (size_t)(k0 + r) * H_DIM + n0 + c, isbf16);
        *(bf16x8*)(&Ts[r][c]) = v;
    }
    __syncthreads();
    // store: rows of Wt (n-major). lane = output row -> LDS reads contiguous per row.
    const int wr = tid & 63;          // output row within tile (n)
    const int wcg = (tid >> 6) * 8;   // k-chunk base
    #pragma unroll
    for (int j = 0; j < 2; j++) {
        int wc = wcg + j * 32;
        bf16x8 o;
        #pragma unroll
        for (int u = 0; u < 8; u++) o[u] = Ts[wc + u][wr];
        *(bf16x8*)(&out[(size_t)(n0 + wr) * H_DIM + k0 + wc]) = o;
    }
}

// m97-class 128x128 GEMM: C = A[M,K] * Wt[n][k]^T + bias
// grid (N/128, M/128, 3): z selects Wq/Wk/Wv and scatter target.
// z=0,1: scatter [B,H,S,D] (Q,K). z=2: scatter V^T [B,H,D,S].
__global__ __launch_bounds__(256) void gemm_qkv_kernel(
    const bf16_t* __restrict__ A, const bf16_t* __restrict__ Wts,
    const void* __restrict__ b0, const void* __restrict__ b1, const void* __restrict__ b2,
    bf16_t* __restrict__ qws, bf16_t* __restrict__ kws, bf16_t* __restrict__ vtws,
    const int* __restrict__ flags)
{
    const int isbf16 = flags[0];
    const int z = blockIdx.z;
    const bf16_t* Wt = Wts + (size_t)z * H_DIM * H_DIM;
    const void* bias = (z == 0) ? b0 : (z == 1) ? b1 : b2;
    bf16_t* dst = (z == 0) ? qws : (z == 1) ? kws : vtws;

    __shared__ __attribute__((aligned(16))) bf16_t As[4][128][8];
    __shared__ __attribute__((aligned(16))) bf16_t Bs[4][128][8];

    const int tid  = threadIdx.x;
    const int lane = tid & 63;
    const int wid  = tid >> 6;
    const int quad = lane >> 4;
    const int l16  = lane & 15;
    const int wm   = (wid >> 1) * 64;
    const int wn   = (wid & 1) * 64;
    const int m0   = blockIdx.y * 128;
    const int n0   = blockIdx.x * 128;

    f32x4 acc[4][4] = {};

    for (int k0 = 0; k0 < H_DIM; k0 += 32) {
        #pragma unroll
        for (int j = 0; j < 2; j++) {
            int slot = j * 256 + tid;
            int k8 = slot >> 7, row = slot & 127;
            GLOAD16(A  + (size_t)(m0 + row) * H_DIM + k0 + k8 * 8, (bf16_t*)As + slot * 8);
            GLOAD16(Wt + (size_t)(n0 + row) * H_DIM + k0 + k8 * 8, (bf16_t*)Bs + slot * 8);
        }
        __syncthreads();
        bf16x8 af[4], bfr[4];
        #pragma unroll
        for (int i = 0; i < 4; i++) {
            af[i]  = *(const bf16x8*)(&As[quad][wm + i * 16 + l16][0]);
            bfr[i] = *(const bf16x8*)(&Bs[quad][wn + i * 16 + l16][0]);
        }
        #pragma unroll
        for (int mi = 0; mi < 4; mi++)
            #pragma unroll
            for (int ni = 0; ni < 4; ni++)
                acc[mi][ni] = MFMA16(af[mi], bfr[ni], acc[mi][ni]);
        __syncthreads();
    }

    // C/D layout: col = lane&15, row = quad*4 + reg
    #pragma unroll
    for (int ni = 0; ni < 4; ni++) {
        int col = n0 + wn + ni * 16 + l16;
        int h = col >> 7, d = col & (HEAD_DIM - 1);
        float bv = readf(bias, col, isbf16);
        #pragma unroll
        for (int mi = 0; mi < 4; mi++) {
            int row0 = m0 + wm + mi * 16 + quad * 4;
            int b = row0 >> 11;
            if (z < 2) {
                #pragma unroll
                for (int r = 0; r < 4; r++) {
                    int s = (row0 + r) & (SEQ - 1);
                    dst[((size_t)(b * N_HEADS + h) * SEQ + s) * HEAD_DIM + d] =
                        (bf16_t)(acc[mi][ni][r] + bv);
                }
            } else {
                int s0 = row0 & (SEQ - 1);
                bf16_t o[4];
                #pragma unroll
                for (int r = 0; r < 4; r++) o[r] = (bf16_t)(acc[mi][ni][r] + bv);
                *(unsigned long long*)(&dst[((size_t)(b * N_HEADS + h) * HEAD_DIM + d) * SEQ + s0]) =
                    *(unsigned long long*)o;
            }
        }
    }
}

// out-projection: C[M,N] = ctx * Wot^T + bo, output dtype per flag
__global__ __launch_bounds__(256) void gemm_out_kernel(
    const bf16_t* __restrict__ A, const bf16_t* __restrict__ Wt,
    const void* __restrict__ bias, void* __restrict__ C,
    const int* __restrict__ flags)
{
    const int isbf16 = flags[0];
    __shared__ __attribute__((aligned(16))) bf16_t As[4][128][8];
    __shared__ __attribute__((aligned(16))) bf16_t Bs[4][128][8];

    const int tid  = threadIdx.x;
    const int lane = tid & 63;
    const int wid  = tid >> 6;
    const int quad = lane >> 4;
    const int l16  = lane & 15;
    const int wm   = (wid >> 1) * 64;
    const int wn   = (wid & 1) * 64;
    const int m0   = blockIdx.y * 128;
    const int n0   = blockIdx.x * 128;

    f32x4 acc[4][4] = {};

    for (int k0 = 0; k0 < H_DIM; k0 += 32) {
        #pragma unroll
        for (int j = 0; j < 2; j++) {
            int slot = j * 256 + tid;
            int k8 = slot >> 7, row = slot & 127;
            GLOAD16(A  + (size_t)(m0 + row) * H_DIM + k0 + k8 * 8, (bf16_t*)As + slot * 8);
            GLOAD16(Wt + (size_t)(n0 + row) * H_DIM + k0 + k8 * 8, (bf16_t*)Bs + slot * 8);
        }
        __syncthreads();
        bf16x8 af[4], bfr[4];
        #pragma unroll
        for (int i = 0; i < 4; i++) {
            af[i]  = *(const bf16x8*)(&As[quad][wm + i * 16 + l16][0]);
            bfr[i] = *(const bf16x8*)(&Bs[quad][wn + i * 16 + l16][0]);
        }
        #pragma unroll
        for (int mi = 0; mi < 4; mi++)
            #pragma unroll
            for (int ni = 0; ni < 4; ni++)
                acc[mi][ni] = MFMA16(af[mi], bfr[ni], acc[mi][ni]);
        __syncthreads();
    }

    #pragma unroll
    for (int ni = 0; ni < 4; ni++) {
        int col = n0 + wn + ni * 16 + l16;
        float bv = readf(bias, col, isbf16);
        #pragma unroll
        for (int mi = 0; mi < 4; mi++) {
            int row0 = m0 + wm + mi * 16 + quad * 4;
            #pragma unroll
            for (int r = 0; r < 4; r++) {
                float v = acc[mi][ni][r] + bv;
                if (isbf16) ((bf16_t*)C)[(size_t)(row0 + r) * H_DIM + col] = (bf16_t)v;
                else        ((float*)C)[(size_t)(row0 + r) * H_DIM + col]  = v;
            }
        }
    }
}

// Barrier-free flash attention. Q,K [B,H,S,D]; Vt [B,H,D,S]; ctx [B,S,H*D]. All bf16.
__global__ __launch_bounds__(256) void attn_kernel(
    const bf16_t* __restrict__ Q, const bf16_t* __restrict__ K,
    const bf16_t* __restrict__ Vt, const int* __restrict__ mask,
    const int* __restrict__ flags, bf16_t* __restrict__ ctx)
{
    __shared__ __attribute__((aligned(16))) bf16_t Pl[4][16][72];  // per-wave

    const int tid  = threadIdx.x;
    const int lane = tid & 63;
    const int wid  = tid >> 6;
    const int quad = lane >> 4;
    const int l16  = lane & 15;

    const int bh = blockIdx.y;
    const int b  = bh >> 4, h = bh & 15;
    const int q_base = blockIdx.x * 64 + wid * 16;
    const int maskAll = flags[1];

    const bf16_t* Qp = Q  + (size_t)bh * SEQ * HEAD_DIM;
    const bf16_t* Kp = K  + (size_t)bh * SEQ * HEAD_DIM;
    const bf16_t* Vp = Vt + (size_t)bh * HEAD_DIM * SEQ;
    const int*    mp = mask + (size_t)b * SEQ * SEQ;

    // Q fragments: A[m=l16][k=quad*8+j], 4 k-steps over D=128
    bf16x8 qf[4];
    #pragma unroll
    for (int t = 0; t < 4; t++)
        qf[t] = *(const bf16x8*)(Qp + (size_t)(q_base + l16) * HEAD_DIM + t * 32 + quad * 8);

    // softmax state in log2 domain
    const float CS = 0.1275260013f;  // (1/sqrt(128)) * log2(e)
    float m_r[4], l_r[4];
    #pragma unroll
    for (int r = 0; r < 4; r++) { m_r[r] = -1e30f; l_r[r] = 0.0f; }
    f32x4 o_acc[8] = {};

    for (int kt = 0; kt < SEQ / 64; kt++) {
        const int key0 = kt * 64;

        // S = Q K^T   (B-operand from K rows: lane = key, regs = d)
        f32x4 s_acc[4];
        #pragma unroll
        for (int nt = 0; nt < 4; nt++) {
            f32x4 a = {};
            #pragma unroll
            for (int t = 0; t < 4; t++) {
                bf16x8 kf = *(const bf16x8*)(Kp + (size_t)(key0 + nt * 16 + l16) * HEAD_DIM + t * 32 + quad * 8);
                a = MFMA16(qf[t], kf, a);
            }
            s_acc[nt] = a;
        }

        float p2[4][4];
        #pragma unroll
        for (int nt = 0; nt < 4; nt++)
            #pragma unroll
            for (int r = 0; r < 4; r++)
                p2[nt][r] = s_acc[nt][r] * CS;

        if (!maskAll) {  // uniform branch; exact semantics for arbitrary masks
            #pragma unroll
            for (int nt = 0; nt < 4; nt++) {
                int key = key0 + nt * 16 + l16;
                #pragma unroll
                for (int r = 0; r < 4; r++) {
                    int q = q_base + quad * 4 + r;
                    if (mp[(size_t)q * SEQ + key] == 0) p2[nt][r] = -1e30f;
                }
            }
        }

        #pragma unroll
        for (int r = 0; r < 4; r++) {
            float tmax = fmaxf(fmaxf(p2[0][r], p2[1][r]), fmaxf(p2[2][r], p2[3][r]));
            #pragma unroll
            for (int off = 1; off < 16; off <<= 1)
                tmax = fmaxf(tmax, __shfl_xor(tmax, off));
            float mnew  = fmaxf(m_r[r], tmax);
            float alpha = exp2f(m_r[r] - mnew);
            m_r[r] = mnew;
            float rsum = 0.0f;
            #pragma unroll
            for (int nt = 0; nt < 4; nt++) {
                float pv = exp2f(p2[nt][r] - mnew);
                p2[nt][r] = pv;
                rsum += pv;
            }
            #pragma unroll
            for (int off = 1; off < 16; off <<= 1)
                rsum += __shfl_xor(rsum, off);
            l_r[r] = l_r[r] * alpha + rsum;
            #pragma unroll
            for (int dn = 0; dn < 8; dn++)
                o_acc[dn][r] *= alpha;
        }

        // P: C-layout -> per-wave LDS -> A-layout (no barrier: same-wave roundtrip)
        #pragma unroll
        for (int nt = 0; nt < 4; nt++)
            #pragma unroll
            for (int r = 0; r < 4; r++)
                Pl[wid][quad * 4 + r][nt * 16 + l16] = (bf16_t)p2[nt][r];

        // O += P V   (B-operand from V^T rows: lane = d, regs = key; global, contiguous)
        #pragma unroll
        for (int t = 0; t < 2; t++) {
            bf16x8 pf = *(const bf16x8*)(&Pl[wid][l16][t * 32 + quad * 8]);
            #pragma unroll
            for (int dn = 0; dn < 8; dn++) {
                bf16x8 vf = *(const bf16x8*)(Vp + (size_t)(dn * 16 + l16) * SEQ + key0 + t * 32 + quad * 8);
                o_acc[dn] = MFMA16(pf, vf, o_acc[dn]);
            }
        }
    }

    #pragma unroll
    for (int dn = 0; dn < 8; dn++) {
        #pragma unroll
        for (int r = 0; r < 4; r++) {
            int q = q_base + quad * 4 + r;
            int d = dn * 16 + l16;
            float v = o_acc[dn][r] / l_r[r];
            ctx[((size_t)(b * SEQ + q) * N_HEADS + h) * HEAD_DIM + d] = (bf16_t)v;
        }
    }
}

extern "C" void kernel_launch(void* const* d_in, const int* in_sizes, int n_in,
                              void* d_out, int out_size, void* d_ws, size_t ws_size,
                              hipStream_t stream) {
    const void* X    = d_in[0];
    const int*  mask = (const int*)d_in[1];
    const void* Wq   = d_in[2];
    const void* bq   = d_in[3];
    const void* Wk   = d_in[4];
    const void* bk   = d_in[5];
    const void* Wv   = d_in[6];
    const void* bv   = d_in[7];
    const void* Wo   = d_in[8];
    const void* bo   = d_in[9];

    const size_t NE = (size_t)BATCH * SEQ * H_DIM;   // 8388608
    const size_t NW = (size_t)H_DIM * H_DIM;         // 4194304

    int*    flags = (int*)d_ws;
    bf16_t* Xb    = (bf16_t*)((char*)d_ws + 256);
    bf16_t* Wts   = Xb + NE;        // 4 transposed weights [n][k]
    bf16_t* qws   = Wts + 4 * NW;   // [B,H,S,D]
    bf16_t* kws   = qws + NE;       // [B,H,S,D]
    bf16_t* vtws  = kws + NE;       // [B,H,D,S]
    bf16_t* cws   = vtws + NE;      // ctx [B,S,H*D]

    detect_kernel<<<1, 256, 0, stream>>>((const unsigned int*)X, flags);
    maskcheck_kernel<<<(BATCH * SEQ * SEQ) / (256 * 8), 256, 0, stream>>>(mask, flags);
    convert_kernel<<<NE / (256 * 8), 256, 0, stream>>>(X, Xb, flags);
    transpose_kernel<<<dim3(32, 32, 4), 256, 0, stream>>>(Wq, Wk, Wv, Wo, Wts, flags);
    gemm_qkv_kernel<<<dim3(H_DIM / 128, (BATCH * SEQ) / 128, 3), 256, 0, stream>>>(
        Xb, Wts, bq, bk, bv, qws, kws, vtws, flags);
    attn_kernel<<<dim3(SEQ / 64, BATCH * N_HEADS), 256, 0, stream>>>(
        qws, kws, vtws, mask, flags, cws);
    gemm_out_kernel<<<dim3(H_DIM / 128, (BATCH * SEQ) / 128), 256, 0, stream>>>(
        cws, Wts + 3 * NW, bo, d_out, flags);
}

// Round 4
// 701.314 us; speedup vs baseline: 1.7787x; 1.6748x over previous
//
#include <hip/hip_runtime.h>
#include <hip/hip_bf16.h>

#define H_DIM 2048
#define N_HEADS 16
#define HEAD_DIM 128
#define BATCH 2
#define SEQ 2048

typedef __bf16 bf16_t;
typedef __bf16 bf16x8 __attribute__((ext_vector_type(8)));
typedef float f32x4 __attribute__((ext_vector_type(4)));

#define MFMA16(a, b, c) __builtin_amdgcn_mfma_f32_16x16x32_bf16((a), (b), (c), 0, 0, 0)

// async global->LDS, 16 B per lane. LDS side must be uniform-base + lane*16.
#define GLOAD16(gp, lp) __builtin_amdgcn_global_load_lds( \
    (const __attribute__((address_space(1))) void*)(gp),  \
    (__attribute__((address_space(3))) void*)(lp), 16, 0, 0)

// flags[0] = inputs stored as bf16 (1) or fp32 (0); flags[1] = mask all-ones
__global__ __launch_bounds__(256) void detect_kernel(const unsigned int* __restrict__ X,
                                                     int* __restrict__ flags) {
    __shared__ int cnt[256];
    int t = threadIdx.x;
    int c = 0;
    for (int i = 0; i < 16; i++) {
        unsigned w  = X[t * 16 + i];
        unsigned lo = w & 0xFFFFu;
        unsigned e  = (lo >> 7) & 0xFFu;
        if (lo == 0u || (e >= 100u && e <= 141u)) c++;
    }
    cnt[t] = c;
    __syncthreads();
    for (int s = 128; s > 0; s >>= 1) {
        if (t < s) cnt[t] += cnt[t + s];
        __syncthreads();
    }
    if (t == 0) { flags[0] = (cnt[0] >= 2048) ? 1 : 0; flags[1] = 1; }
}

__global__ __launch_bounds__(256) void maskcheck_kernel(const int* __restrict__ mask,
                                                        int* __restrict__ flags) {
    size_t i = ((size_t)blockIdx.x * 256 + threadIdx.x) * 8;
    const int4* p = (const int4*)(mask + i);
    int4 a = p[0], b = p[1];
    int all = (a.x != 0) & (a.y != 0) & (a.z != 0) & (a.w != 0) &
              (b.x != 0) & (b.y != 0) & (b.z != 0) & (b.w != 0);
    if (!all) atomicAnd(&flags[1], 0);
}

__device__ inline bf16x8 load8(const void* __restrict__ p, size_t idx, int isbf16) {
    if (isbf16) {
        return *(const bf16x8*)((const bf16_t*)p + idx);
    } else {
        const float* f = (const float*)p + idx;
        float4 a = *(const float4*)f;
        float4 b = *(const float4*)(f + 4);
        bf16x8 r;
        r[0] = (bf16_t)a.x; r[1] = (bf16_t)a.y; r[2] = (bf16_t)a.z; r[3] = (bf16_t)a.w;
        r[4] = (bf16_t)b.x; r[5] = (bf16_t)b.y; r[6] = (bf16_t)b.z; r[7] = (bf16_t)b.w;
        return r;
    }
}

__device__ inline float readf(const void* __restrict__ p, int idx, int isbf16) {
    return isbf16 ? (float)((const bf16_t*)p)[idx] : ((const float*)p)[idx];
}

// X (fp32 or bf16) -> Xb (bf16), 8 elems/thread
__global__ __launch_bounds__(256) void convert_kernel(const void* __restrict__ X,
                                                      bf16_t* __restrict__ Xb,
                                                      const int* __restrict__ flags) {
    const int isbf16 = flags[0];
    size_t i = ((size_t)blockIdx.x * 256 + threadIdx.x) * 8;
    bf16x8 v = load8(X, i, isbf16);
    *(bf16x8*)(Xb + i) = v;
}

// Wt[z][n][k] = W_z[k][n], bf16 output. grid (32,32,4), 64x64 tiles.
__global__ __launch_bounds__(256) void transpose_kernel(
    const void* __restrict__ W0, const void* __restrict__ W1,
    const void* __restrict__ W2, const void* __restrict__ W3,
    bf16_t* __restrict__ Wts, const int* __restrict__ flags)
{
    const int isbf16 = flags[0];
    const int z = blockIdx.z;
    const void* W = (z == 0) ? W0 : (z == 1) ? W1 : (z == 2) ? W2 : W3;
    bf16_t* out = Wts + (size_t)z * H_DIM * H_DIM;

    __shared__ __attribute__((aligned(16))) bf16_t Ts[64][72];
    const int tid = threadIdx.x;
    const int n0 = blockIdx.x * 64;
    const int k0 = blockIdx.y * 64;

    #pragma unroll
    for (int j = 0; j < 2; j++) {
        int idx = j * 2048 + tid * 8;
        int r = idx >> 6, c = idx & 63;
        bf16x8 v = load8(W, (size_t)(k0 + r) * H_DIM + n0 + c, isbf16);
        *(bf16x8*)(&Ts[r][c]) = v;
    }
    __syncthreads();
    const int wr = tid & 63;
    const int wcg = (tid >> 6) * 8;
    #pragma unroll
    for (int j = 0; j < 2; j++) {
        int wc = wcg + j * 32;
        bf16x8 o;
        #pragma unroll
        for (int u = 0; u < 8; u++) o[u] = Ts[wc + u][wr];
        *(bf16x8*)(&out[(size_t)(n0 + wr) * H_DIM + k0 + wc]) = o;
    }
}

// m97-class 128x128 GEMM: C = A[M,K] * Wt[n][k]^T + bias
// grid (N/128, M/128, 3): z selects Wq/Wk/Wv and scatter target.
// z=0,1: scatter [B,H,S,D] (Q,K). z=2: scatter V^T [B,H,D,S].
__global__ __launch_bounds__(256) void gemm_qkv_kernel(
    const bf16_t* __restrict__ A, const bf16_t* __restrict__ Wts,
    const void* __restrict__ b0, const void* __restrict__ b1, const void* __restrict__ b2,
    bf16_t* __restrict__ qws, bf16_t* __restrict__ kws, bf16_t* __restrict__ vtws,
    const int* __restrict__ flags)
{
    const int isbf16 = flags[0];
    const int z = blockIdx.z;
    const bf16_t* Wt = Wts + (size_t)z * H_DIM * H_DIM;
    const void* bias = (z == 0) ? b0 : (z == 1) ? b1 : b2;
    bf16_t* dst = (z == 0) ? qws : (z == 1) ? kws : vtws;

    __shared__ __attribute__((aligned(16))) bf16_t As[4][128][8];
    __shared__ __attribute__((aligned(16))) bf16_t Bs[4][128][8];

    const int tid  = threadIdx.x;
    const int lane = tid & 63;
    const int wid  = tid >> 6;
    const int quad = lane >> 4;
    const int l16  = lane & 15;
    const int wm   = (wid >> 1) * 64;
    const int wn   = (wid & 1) * 64;
    const int m0   = blockIdx.y * 128;
    const int n0   = blockIdx.x * 128;

    f32x4 acc[4][4] = {};

    for (int k0 = 0; k0 < H_DIM; k0 += 32) {
        #pragma unroll
        for (int j = 0; j < 2; j++) {
            int slot = j * 256 + tid;
            int k8 = slot >> 7, row = slot & 127;
            GLOAD16(A  + (size_t)(m0 + row) * H_DIM + k0 + k8 * 8, (bf16_t*)As + slot * 8);
            GLOAD16(Wt + (size_t)(n0 + row) * H_DIM + k0 + k8 * 8, (bf16_t*)Bs + slot * 8);
        }
        __syncthreads();
        bf16x8 af[4], bfr[4];
        #pragma unroll
        for (int i = 0; i < 4; i++) {
            af[i]  = *(const bf16x8*)(&As[quad][wm + i * 16 + l16][0]);
            bfr[i] = *(const bf16x8*)(&Bs[quad][wn + i * 16 + l16][0]);
        }
        #pragma unroll
        for (int mi = 0; mi < 4; mi++)
            #pragma unroll
            for (int ni = 0; ni < 4; ni++)
                acc[mi][ni] = MFMA16(af[mi], bfr[ni], acc[mi][ni]);
        __syncthreads();
    }

    #pragma unroll
    for (int ni = 0; ni < 4; ni++) {
        int col = n0 + wn + ni * 16 + l16;
        int h = col >> 7, d = col & (HEAD_DIM - 1);
        float bv = readf(bias, col, isbf16);
        #pragma unroll
        for (int mi = 0; mi < 4; mi++) {
            int row0 = m0 + wm + mi * 16 + quad * 4;
            int b = row0 >> 11;
            if (z < 2) {
                #pragma unroll
                for (int r = 0; r < 4; r++) {
                    int s = (row0 + r) & (SEQ - 1);
                    dst[((size_t)(b * N_HEADS + h) * SEQ + s) * HEAD_DIM + d] =
                        (bf16_t)(acc[mi][ni][r] + bv);
                }
            } else {
                int s0 = row0 & (SEQ - 1);
                bf16_t o[4];
                #pragma unroll
                for (int r = 0; r < 4; r++) o[r] = (bf16_t)(acc[mi][ni][r] + bv);
                *(unsigned long long*)(&dst[((size_t)(b * N_HEADS + h) * HEAD_DIM + d) * SEQ + s0]) =
                    *(unsigned long long*)o;
            }
        }
    }
}

// out-projection: C[M,N] = ctx * Wot^T + bo, output dtype per flag
__global__ __launch_bounds__(256) void gemm_out_kernel(
    const bf16_t* __restrict__ A, const bf16_t* __restrict__ Wt,
    const void* __restrict__ bias, void* __restrict__ C,
    const int* __restrict__ flags)
{
    const int isbf16 = flags[0];
    __shared__ __attribute__((aligned(16))) bf16_t As[4][128][8];
    __shared__ __attribute__((aligned(16))) bf16_t Bs[4][128][8];

    const int tid  = threadIdx.x;
    const int lane = tid & 63;
    const int wid  = tid >> 6;
    const int quad = lane >> 4;
    const int l16  = lane & 15;
    const int wm   = (wid >> 1) * 64;
    const int wn   = (wid & 1) * 64;
    const int m0   = blockIdx.y * 128;
    const int n0   = blockIdx.x * 128;

    f32x4 acc[4][4] = {};

    for (int k0 = 0; k0 < H_DIM; k0 += 32) {
        #pragma unroll
        for (int j = 0; j < 2; j++) {
            int slot = j * 256 + tid;
            int k8 = slot >> 7, row = slot & 127;
            GLOAD16(A  + (size_t)(m0 + row) * H_DIM + k0 + k8 * 8, (bf16_t*)As + slot * 8);
            GLOAD16(Wt + (size_t)(n0 + row) * H_DIM + k0 + k8 * 8, (bf16_t*)Bs + slot * 8);
        }
        __syncthreads();
        bf16x8 af[4], bfr[4];
        #pragma unroll
        for (int i = 0; i < 4; i++) {
            af[i]  = *(const bf16x8*)(&As[quad][wm + i * 16 + l16][0]);
            bfr[i] = *(const bf16x8*)(&Bs[quad][wn + i * 16 + l16][0]);
        }
        #pragma unroll
        for (int mi = 0; mi < 4; mi++)
            #pragma unroll
            for (int ni = 0; ni < 4; ni++)
                acc[mi][ni] = MFMA16(af[mi], bfr[ni], acc[mi][ni]);
        __syncthreads();
    }

    #pragma unroll
    for (int ni = 0; ni < 4; ni++) {
        int col = n0 + wn + ni * 16 + l16;
        float bv = readf(bias, col, isbf16);
        #pragma unroll
        for (int mi = 0; mi < 4; mi++) {
            int row0 = m0 + wm + mi * 16 + quad * 4;
            #pragma unroll
            for (int r = 0; r < 4; r++) {
                float v = acc[mi][ni][r] + bv;
                if (isbf16) ((bf16_t*)C)[(size_t)(row0 + r) * H_DIM + col] = (bf16_t)v;
                else        ((float*)C)[(size_t)(row0 + r) * H_DIM + col]  = v;
            }
        }
    }
}

// Flash attention, m97-style double-buffered LDS staging of K and V^T tiles.
// Q,K [B,H,S,D]; Vt [B,H,D,S]; ctx [B,S,H*D]. All bf16.
// One block = (b,h) x 64 queries; 4 waves each own 16 queries.
__global__ __launch_bounds__(256) void attn_kernel(
    const bf16_t* __restrict__ Q, const bf16_t* __restrict__ K,
    const bf16_t* __restrict__ Vt, const int* __restrict__ mask,
    const int* __restrict__ flags, bf16_t* __restrict__ ctx)
{
    // quad-major tiles: fragment reads are contiguous 16B/lane (conflict-free)
    __shared__ __attribute__((aligned(16))) bf16_t Ks[2][16][64][8];  // [buf][k8=d/8][key][8]
    __shared__ __attribute__((aligned(16))) bf16_t Vs[2][8][128][8];  // [buf][kq=key/8][d][8]
    __shared__ __attribute__((aligned(16))) bf16_t Pl[4][16][72];     // per-wave P roundtrip

    const int tid  = threadIdx.x;
    const int lane = tid & 63;
    const int wid  = tid >> 6;
    const int quad = lane >> 4;
    const int l16  = lane & 15;

    const int bh = blockIdx.y;
    const int b  = bh >> 4, h = bh & 15;
    const int q_base = blockIdx.x * 64 + wid * 16;
    const int maskAll = flags[1];

    const bf16_t* Qp = Q  + (size_t)bh * SEQ * HEAD_DIM;
    const bf16_t* Kp = K  + (size_t)bh * SEQ * HEAD_DIM;
    const bf16_t* Vp = Vt + (size_t)bh * HEAD_DIM * SEQ;
    const int*    mp = mask + (size_t)b * SEQ * SEQ;

    // Q fragments: A[m=l16][k=quad*8+j], 4 k-steps over D=128 (held in regs)
    bf16x8 qf[4];
    #pragma unroll
    for (int t = 0; t < 4; t++)
        qf[t] = *(const bf16x8*)(Qp + (size_t)(q_base + l16) * HEAD_DIM + t * 32 + quad * 8);

    const float CS = 0.1275260013f;  // (1/sqrt(128)) * log2(e)
    float m_r[4], l_r[4];
    #pragma unroll
    for (int r = 0; r < 4; r++) { m_r[r] = -1e30f; l_r[r] = 0.0f; }
    f32x4 o_acc[8] = {};

    // stage tile kt into buffer bb (8 GLOAD16 per thread-slot pass)
    auto stage = [&](int kt, int bb) {
        const int key0 = kt * 64;
        #pragma unroll
        for (int j = 0; j < 4; j++) {
            int slot = j * 256 + tid;
            int krow = slot & 63, k8 = slot >> 6;
            GLOAD16(Kp + (size_t)(key0 + krow) * HEAD_DIM + k8 * 8,
                    (bf16_t*)(&Ks[bb][0][0][0]) + slot * 8);
        }
        #pragma unroll
        for (int j = 0; j < 4; j++) {
            int slot = j * 256 + tid;
            int d = slot & 127, kq = slot >> 7;
            GLOAD16(Vp + (size_t)d * SEQ + key0 + kq * 8,
                    (bf16_t*)(&Vs[bb][0][0][0]) + slot * 8);
        }
    };

    stage(0, 0);

    const int NKT = SEQ / 64;
    for (int kt = 0; kt < NKT; kt++) {
        const int bb = kt & 1;
        const int key0 = kt * 64;
        __syncthreads();                 // drains tile kt's loads; prev reads done
        if (kt + 1 < NKT) stage(kt + 1, bb ^ 1);   // in flight during compute

        // S = Q K^T  (B-operand: n=key=l16, k=d)
        f32x4 s_acc[4];
        #pragma unroll
        for (int nt = 0; nt < 4; nt++) {
            f32x4 a = {};
            #pragma unroll
            for (int t = 0; t < 4; t++) {
                bf16x8 kf = *(const bf16x8*)(&Ks[bb][t * 4 + quad][nt * 16 + l16][0]);
                a = MFMA16(qf[t], kf, a);
            }
            s_acc[nt] = a;
        }

        float p2[4][4];
        #pragma unroll
        for (int nt = 0; nt < 4; nt++)
            #pragma unroll
            for (int r = 0; r < 4; r++)
                p2[nt][r] = s_acc[nt][r] * CS;

        if (!maskAll) {
            #pragma unroll
            for (int nt = 0; nt < 4; nt++) {
                int key = key0 + nt * 16 + l16;
                #pragma unroll
                for (int r = 0; r < 4; r++) {
                    int q = q_base + quad * 4 + r;
                    if (mp[(size_t)q * SEQ + key] == 0) p2[nt][r] = -1e30f;
                }
            }
        }

        #pragma unroll
        for (int r = 0; r < 4; r++) {
            float tmax = fmaxf(fmaxf(p2[0][r], p2[1][r]), fmaxf(p2[2][r], p2[3][r]));
            #pragma unroll
            for (int off = 1; off < 16; off <<= 1)
                tmax = fmaxf(tmax, __shfl_xor(tmax, off));
            float mnew  = fmaxf(m_r[r], tmax);
            float alpha = exp2f(m_r[r] - mnew);
            m_r[r] = mnew;
            float rsum = 0.0f;
            #pragma unroll
            for (int nt = 0; nt < 4; nt++) {
                float pv = exp2f(p2[nt][r] - mnew);
                p2[nt][r] = pv;
                rsum += pv;
            }
            #pragma unroll
            for (int off = 1; off < 16; off <<= 1)
                rsum += __shfl_xor(rsum, off);
            l_r[r] = l_r[r] * alpha + rsum;
            #pragma unroll
            for (int dn = 0; dn < 8; dn++)
                o_acc[dn][r] *= alpha;
        }

        // P: C-layout -> per-wave LDS -> A-layout (same-wave roundtrip, no barrier)
        #pragma unroll
        for (int nt = 0; nt < 4; nt++)
            #pragma unroll
            for (int r = 0; r < 4; r++)
                Pl[wid][quad * 4 + r][nt * 16 + l16] = (bf16_t)p2[nt][r];

        // O += P V  (B-operand: n=d=l16-row, k=key)
        #pragma unroll
        for (int t = 0; t < 2; t++) {
            bf16x8 pf = *(const bf16x8*)(&Pl[wid][l16][t * 32 + quad * 8]);
            #pragma unroll
            for (int dn = 0; dn < 8; dn++) {
                bf16x8 vf = *(const bf16x8*)(&Vs[bb][t * 4 + quad][dn * 16 + l16][0]);
                o_acc[dn] = MFMA16(pf, vf, o_acc[dn]);
            }
        }
    }

    #pragma unroll
    for (int dn = 0; dn < 8; dn++) {
        #pragma unroll
        for (int r = 0; r < 4; r++) {
            int q = q_base + quad * 4 + r;
            int d = dn * 16 + l16;
            float v = o_acc[dn][r] / l_r[r];
            ctx[((size_t)(b * SEQ + q) * N_HEADS + h) * HEAD_DIM + d] = (bf16_t)v;
        }
    }
}

extern "C" void kernel_launch(void* const* d_in, const int* in_sizes, int n_in,
                              void* d_out, int out_size, void* d_ws, size_t ws_size,
                              hipStream_t stream) {
    const void* X    = d_in[0];
    const int*  mask = (const int*)d_in[1];
    const void* Wq   = d_in[2];
    const void* bq   = d_in[3];
    const void* Wk   = d_in[4];
    const void* bk   = d_in[5];
    const void* Wv   = d_in[6];
    const void* bv   = d_in[7];
    const void* Wo   = d_in[8];
    const void* bo   = d_in[9];

    const size_t NE = (size_t)BATCH * SEQ * H_DIM;   // 8388608
    const size_t NW = (size_t)H_DIM * H_DIM;         // 4194304

    int*    flags = (int*)d_ws;
    bf16_t* Xb    = (bf16_t*)((char*)d_ws + 256);
    bf16_t* Wts   = Xb + NE;        // 4 transposed weights [n][k]
    bf16_t* qws   = Wts + 4 * NW;   // [B,H,S,D]
    bf16_t* kws   = qws + NE;       // [B,H,S,D]
    bf16_t* vtws  = kws + NE;       // [B,H,D,S]
    bf16_t* cws   = vtws + NE;      // ctx [B,S,H*D]

    detect_kernel<<<1, 256, 0, stream>>>((const unsigned int*)X, flags);
    maskcheck_kernel<<<(BATCH * SEQ * SEQ) / (256 * 8), 256, 0, stream>>>(mask, flags);
    convert_kernel<<<NE / (256 * 8), 256, 0, stream>>>(X, Xb, flags);
    transpose_kernel<<<dim3(32, 32, 4), 256, 0, stream>>>(Wq, Wk, Wv, Wo, Wts, flags);
    gemm_qkv_kernel<<<dim3(H_DIM / 128, (BATCH * SEQ) / 128, 3), 256, 0, stream>>>(
        Xb, Wts, bq, bk, bv, qws, kws, vtws, flags);
    attn_kernel<<<dim3(SEQ / 64, BATCH * N_HEADS), 256, 0, stream>>>(
        qws, kws, vtws, mask, flags, cws);
    gemm_out_kernel<<<dim3(H_DIM / 128, (BATCH * SEQ) / 128), 256, 0, stream>>>(
        cws, Wts + 3 * NW, bo, d_out, flags);
}